// Round 15
// baseline (221.206 us; speedup 1.0000x reference)
//
#include <hip/hip_runtime.h>
#include <hip/hip_bf16.h>

// Problem constants
#define BB 4
#define SS 4096
#define DM 1024
#define HH 16
#define PP 32
#define RR 8
#define DD 64
#define NTOK (BB*SS)          // 16384 tokens
#define MM NTOK               // GEMM M
#define NN DM                 // GEMM N
#define KK DM                 // GEMM K

typedef __attribute__((ext_vector_type(8))) short short8;
typedef __attribute__((ext_vector_type(4))) float floatx4;
typedef __attribute__((ext_vector_type(2))) float floatx2;

static __device__ inline short f2bf(float f) {
    union { __hip_bfloat16 b; short s; } u; u.b = __float2bfloat16(f); return u.s;
}
static __device__ inline short8 pack8(float4 lo, float4 hi) {
    short8 r;
    r[0] = f2bf(lo.x); r[1] = f2bf(lo.y); r[2] = f2bf(lo.z); r[3] = f2bf(lo.w);
    r[4] = f2bf(hi.x); r[5] = f2bf(hi.y); r[6] = f2bf(hi.z); r[7] = f2bf(hi.w);
    return r;
}

// Fast RNE bf16 pack: identical bits to __float2bfloat16 for finite inputs.
static __device__ inline unsigned bfr(float f) {
    unsigned u = __float_as_uint(f);
    return u + 0x7fffu + ((u >> 16) & 1u);
}
static __device__ inline int pk2(float a, float b) {  // low16=bf(a), high16=bf(b)
    return __builtin_amdgcn_perm(bfr(b), bfr(a), 0x07060302);
}
static __device__ inline short8 pk8(float4 lo, float4 hi) {
    union { short8 s; int i[4]; } r;
    r.i[0] = pk2(lo.x, lo.y); r.i[1] = pk2(lo.z, lo.w);
    r.i[2] = pk2(hi.x, hi.y); r.i[3] = pk2(hi.z, hi.w);
    return r.s;
}

// Exact top-4 ladder insert: selection network (fmax/fmin only), order-
// independent — produces exact order statistics, no rounding.
#define LADDER_INSERT(v_, aa_, b2_, c3_, d4_)                  \
    {                                                          \
        float v = (v_);                                        \
        float na = fmaxf(aa_, v); v = fminf(aa_, v); aa_ = na; \
        float nb = fmaxf(b2_, v); v = fminf(b2_, v); b2_ = nb; \
        float nc = fmaxf(c3_, v); v = fminf(c3_, v); c3_ = nc; \
        d4_ = fmaxf(d4_, v);                                   \
    }

// ---------------------------------------------------------------------------
// Kernel 1 (pre_fused v3): router+packer ∥ weight converts.
// R14 counters: fusion cut FETCH 69.7->37 MB but dur flat at ~48 us ->
// router is VALU-issue/latency bound, not memory bound. v3 attacks the two
// biggest instruction blocks, both exactness-preserving:
//  (a) logits: token-pairs packed into float2 accumulators via
//      __builtin_elementwise_fma (guaranteed fused -> v_pk_fma_f32; each
//      component's chain is the exact R14 fmac sequence -> BIT-IDENTICAL
//      logits, zero top-k flip risk). 512 -> 256 FMA instrs/wave.
//  (b) top-k: 64-lane parallel exact selection — each l4 group ladders its
//      8 experts, two shfl_xor merges insert the partner's top-4 (exact:
//      union-top4 is contained in the union of group-top4s; fmax/fmin
//      selection has no rounding). 224 -> ~130 instrs, thresh/a1 land in
//      ALL lanes (broadcast shfls dropped).
// ---------------------------------------------------------------------------
__global__ __launch_bounds__(256) void pre_fused(const float* __restrict__ x,
                                                 const float* __restrict__ Wr,
                                                 const int* __restrict__ kp,
                                                 const float* __restrict__ Wo,
                                                 const float* __restrict__ Kst,
                                                 const float* __restrict__ Vst,
                                                 float* __restrict__ gates_g,
                                                 __hip_bfloat16* __restrict__ wsw,
                                                 __hip_bfloat16* __restrict__ kfrag,
                                                 __hip_bfloat16* __restrict__ vfrag,
                                                 __hip_bfloat16* __restrict__ xbf) {
    const int bx = blockIdx.x;

    if (bx >= 4096) {
        if (bx < 4608) {                        // ---- convert_w ----
            int tid = (bx - 4096) * 256 + threadIdx.x;     // 0 .. 131071
            int l = tid & 63;
            int kblk = (tid >> 6) & 31;
            int ntile = tid >> 11;
            int col = ntile * 16 + (l & 15);
            int krow = kblk * 32 + (l >> 4) * 8;
#pragma unroll
            for (int j = 0; j < 8; ++j)
                wsw[(size_t)tid * 8 + j] = __float2bfloat16(Wo[(size_t)(krow + j) * NN + col]);
        } else {                                // ---- convert_kv ----
            int tid = (bx - 4608) * 256 + threadIdx.x;     // 0..65535
            int arr = tid >> 15;
            int idx = tid & 32767;
            int h = idx >> 11, blk = (idx >> 6) & 31, fl = idx & 63;
            int fm = fl & 15, fk = fl >> 4;
            short8 val;
            short* dst;
            if (arr == 0) {
                int mt = blk >> 1, kb = blk & 1;
                int pr = mt * 16 + fm, d0 = kb * 32 + fk * 8;
                const float* src = Kst + ((size_t)h * 256 + pr) * 64 + d0;
                float4 lo = *(const float4*)src, hi = *(const float4*)(src + 4);
                val = pack8(lo, hi);
                dst = (short*)kfrag + (size_t)idx * 8;
            } else {
                int mt = blk >> 3, kb = blk & 7;
                int d = mt * 16 + fm, pr0 = kb * 32 + fk * 8;
                const float* src = Vst + ((size_t)h * 256 + pr0) * 64 + d;
#pragma unroll
                for (int j = 0; j < 8; ++j) val[j] = f2bf(src[j * 64]);
                dst = (short*)vfrag + (size_t)idx * 8;
            }
            *(short8*)dst = val;
        }
        return;
    }

    // ------------------------- router branch -------------------------
    __shared__ __align__(16) char smem[26624];
    float (*xs)[68] = (float (*)[68])smem;               // [0,17408)
    float (*Lg)[36] = (float (*)[36])(smem + 17408);     // [17408,26624)

    const int lane = threadIdx.x & 63;
    const int w = threadIdx.x >> 6;
    const int l15 = lane & 15, l4 = lane >> 4;
    const int tile = bx & 255;
    const int h = bx >> 8;
    const int t0 = tile * 64;

    // ---- stage x tile [64 t x 64 d] into LDS ----
    {
        int row = threadIdx.x >> 2, q = threadIdx.x & 3;
        const float4* src = (const float4*)(x + (size_t)(t0 + row) * DM + h * 64 + q * 16);
        float4 v0 = src[0], v1 = src[1], v2 = src[2], v3 = src[3];
        float4* dst = (float4*)&xs[row][q * 16];
        dst[0] = v0; dst[1] = v1; dst[2] = v2; dst[3] = v3;
    }

    // ---- fused xbf packer (reads L1/L2-hot x; exact R13 packer bits) ----
    {
        const float* srcb = x + (size_t)(t0 + w * 16 + l15) * DM + h * 64 + l4 * 8;
        short* dstb = (short*)xbf + ((size_t)((h * 256 + tile) * 8 + w * 2) * 512) + lane * 8;
#pragma unroll
        for (int kb = 0; kb < 2; ++kb) {
            float4 lo = *(const float4*)(srcb + kb * 32);
            float4 hi = *(const float4*)(srcb + kb * 32 + 4);
            *(short8*)(dstb + kb * 512) = pk8(lo, hi);
        }
    }

    // ---- preload router weights (exact R1 pattern) ----
    const int p = lane & 31, dh = lane >> 5;
    float wreg[32];
    {
        const float* wrp = Wr + (size_t)h * (DD * PP) + dh * 32 * PP + p;
#pragma unroll
        for (int dd = 0; dd < 32; ++dd) wreg[dd] = wrp[dd * PP];
    }
    const int kkv = kp[0];

    __syncthreads();

    // ---- logits: packed float2 (tokens A,B | C,D); per-component fma
    //      chain IDENTICAL to the R14 scalar fmac chain -> bit-identical ----
    for (int it = 0; it < 16; it += 4) {
        const int ta = w * 16 + it;
        floatx2 lab = {0.f, 0.f}, lcd = {0.f, 0.f};
#pragma unroll
        for (int j = 0; j < 8; ++j) {
            float4 qa = *(const float4*)&xs[ta + 0][dh * 32 + 4 * j];
            float4 qb = *(const float4*)&xs[ta + 1][dh * 32 + 4 * j];
            float4 qc = *(const float4*)&xs[ta + 2][dh * 32 + 4 * j];
            float4 qd = *(const float4*)&xs[ta + 3][dh * 32 + 4 * j];
            floatx2 w0 = {wreg[4 * j], wreg[4 * j]};
            floatx2 w1 = {wreg[4 * j + 1], wreg[4 * j + 1]};
            floatx2 w2 = {wreg[4 * j + 2], wreg[4 * j + 2]};
            floatx2 w3 = {wreg[4 * j + 3], wreg[4 * j + 3]};
            floatx2 vx, vy, vz, vw, ux, uy, uz, uw;
            vx[0] = qa.x; vx[1] = qb.x;  ux[0] = qc.x; ux[1] = qd.x;
            vy[0] = qa.y; vy[1] = qb.y;  uy[0] = qc.y; uy[1] = qd.y;
            vz[0] = qa.z; vz[1] = qb.z;  uz[0] = qc.z; uz[1] = qd.z;
            vw[0] = qa.w; vw[1] = qb.w;  uw[0] = qc.w; uw[1] = qd.w;
            lab = __builtin_elementwise_fma(vx, w0, lab);
            lcd = __builtin_elementwise_fma(ux, w0, lcd);
            lab = __builtin_elementwise_fma(vy, w1, lab);
            lcd = __builtin_elementwise_fma(uy, w1, lcd);
            lab = __builtin_elementwise_fma(vz, w2, lab);
            lcd = __builtin_elementwise_fma(uz, w2, lcd);
            lab = __builtin_elementwise_fma(vw, w3, lab);
            lcd = __builtin_elementwise_fma(uw, w3, lcd);
        }
        float la = lab[0], lb = lab[1], lc = lcd[0], ld = lcd[1];
        la += __shfl_xor(la, 32);
        lb += __shfl_xor(lb, 32);
        lc += __shfl_xor(lc, 32);
        ld += __shfl_xor(ld, 32);
        if (lane < 32) {
            Lg[ta + 0][lane] = la;
            Lg[ta + 1][lane] = lb;
            Lg[ta + 2][lane] = lc;
            Lg[ta + 3][lane] = ld;
        }
    }
    __syncthreads();

    // ---- top-k: 64-lane parallel EXACT selection. Token t = w*16+l15;
    //      lane-group l4 ladders experts [l4*8, l4*8+8); two shfl_xor
    //      merges (insert partner's sorted top-4). Pure fmax/fmin
    //      selection network -> exact order statistics, same thresh/a1
    //      bits as the serial ladder. Result lands in ALL lanes. ----
    float thresh, a1;
    {
        const int t = w * 16 + l15;
        const float4* lrow = (const float4*)&Lg[t][l4 * 8];
        float4 qa = lrow[0], qb = lrow[1];
        float aa = -INFINITY, b2 = -INFINITY, c3 = -INFINITY, d4 = -INFINITY;
        LADDER_INSERT(qa.x, aa, b2, c3, d4);
        LADDER_INSERT(qa.y, aa, b2, c3, d4);
        LADDER_INSERT(qa.z, aa, b2, c3, d4);
        LADDER_INSERT(qa.w, aa, b2, c3, d4);
        LADDER_INSERT(qb.x, aa, b2, c3, d4);
        LADDER_INSERT(qb.y, aa, b2, c3, d4);
        LADDER_INSERT(qb.z, aa, b2, c3, d4);
        LADDER_INSERT(qb.w, aa, b2, c3, d4);
#pragma unroll
        for (int m = 16; m <= 32; m <<= 1) {
            float pa = __shfl_xor(aa, m);
            float pb = __shfl_xor(b2, m);
            float pc = __shfl_xor(c3, m);
            float pd = __shfl_xor(d4, m);
            LADDER_INSERT(pa, aa, b2, c3, d4);
            LADDER_INSERT(pb, aa, b2, c3, d4);
            LADDER_INSERT(pc, aa, b2, c3, d4);
            LADDER_INSERT(pd, aa, b2, c3, d4);
        }
        thresh = (kkv >= 4) ? d4 : (kkv == 3 ? c3 : (kkv == 2 ? b2 : aa));
        a1 = aa;
    }

    // ---- gates: all 64 lanes, 8 p-values each; values identical to R14 ----
    {
        const int t = w * 16 + l15;
        const int p8 = l4 * 8;
        const float4* lrow = (const float4*)&Lg[t][p8];
        float4 qa = lrow[0], qb = lrow[1];
        float e0 = (qa.x >= thresh) ? __expf(qa.x - a1) : 0.f;
        float e1 = (qa.y >= thresh) ? __expf(qa.y - a1) : 0.f;
        float e2 = (qa.z >= thresh) ? __expf(qa.z - a1) : 0.f;
        float e3 = (qa.w >= thresh) ? __expf(qa.w - a1) : 0.f;
        float e4 = (qb.x >= thresh) ? __expf(qb.x - a1) : 0.f;
        float e5 = (qb.y >= thresh) ? __expf(qb.y - a1) : 0.f;
        float e6 = (qb.z >= thresh) ? __expf(qb.z - a1) : 0.f;
        float e7 = (qb.w >= thresh) ? __expf(qb.w - a1) : 0.f;
        float part = ((e0 + e1) + (e2 + e3)) + ((e4 + e5) + (e6 + e7));
        part += __shfl_xor(part, 16);
        part += __shfl_xor(part, 32);
        float inv = 1.f / part;
        float* gb = gates_g + ((size_t)(h * 256 + tile) * 32) * 64 + t;
        gb[(p8 + 0) * 64] = e0 * inv;
        gb[(p8 + 1) * 64] = e1 * inv;
        gb[(p8 + 2) * 64] = e2 * inv;
        gb[(p8 + 3) * 64] = e3 * inv;
        gb[(p8 + 4) * 64] = e4 * inv;
        gb[(p8 + 5) * 64] = e5 * inv;
        gb[(p8 + 6) * 64] = e6 * inv;
        gb[(p8 + 7) * 64] = e7 * inv;
    }
}

// ---------------------------------------------------------------------------
// Kernel 2 (attn_mm8): 8-wave attention MFMA kernel. Unchanged from R14
// (out of top-5, < 47.5 us).
// ---------------------------------------------------------------------------
__global__ __launch_bounds__(512, 4) void attn_mm8(const __hip_bfloat16* __restrict__ xbf,
                                                   const __hip_bfloat16* __restrict__ kfrag,
                                                   const __hip_bfloat16* __restrict__ vfrag,
                                                   const float* __restrict__ gates_g,
                                                   __hip_bfloat16* __restrict__ hb) {
    __shared__ __align__(16) short wf[16384];      // 32768 B

    const int lane = threadIdx.x & 63;
    const int w = threadIdx.x >> 6;                // 0..7
    const int l15 = lane & 15, l4 = lane >> 4;
    const int t0 = blockIdx.x * 64;
    const int h = blockIdx.y;

    // ---- preload gates (global, written by pre_fused) ----
    const float* gb = gates_g + ((size_t)(h * 256 + blockIdx.x) * 32) * 64;
    float gv[2][4];
#pragma unroll
    for (int mi = 0; mi < 2; ++mi) {
        const int pidx = (w * 2 + mi) * 2 + (l4 >> 1);
#pragma unroll
        for (int nt = 0; nt < 4; ++nt)
            gv[mi][nt] = gb[pidx * 64 + nt * 16 + l15];
    }

    // ---- scores GEMM operand loads: pre-packed bf16 fragments ----
    const short* xbase = (const short*)xbf + ((size_t)(h * 256 + blockIdx.x) * 8) * 512 + lane * 8;
    short8 xb[4][2];
#pragma unroll
    for (int nt = 0; nt < 4; ++nt)
#pragma unroll
        for (int kb = 0; kb < 2; ++kb)
            xb[nt][kb] = *(const short8*)(xbase + (nt * 2 + kb) * 512);
    short8 ka[2][2];                               // mt = w*2 + mi
#pragma unroll
    for (int mi = 0; mi < 2; ++mi)
#pragma unroll
        for (int kb = 0; kb < 2; ++kb)
            ka[mi][kb] = *(const short8*)((const short*)kfrag +
                          ((size_t)(h * 32 + (w * 2 + mi) * 2 + kb) * 512 + lane * 8));

    // ---- scores GEMM: S^T[pr][t]; per-element kb chains identical ----
    floatx4 acc[2][4] = {};
#pragma unroll
    for (int kb = 0; kb < 2; ++kb)
#pragma unroll
        for (int mi = 0; mi < 2; ++mi)
#pragma unroll
            for (int nt = 0; nt < 4; ++nt)
                acc[mi][nt] = __builtin_amdgcn_mfma_f32_16x16x32_bf16(ka[mi][kb], xb[nt][kb], acc[mi][nt], 0, 0, 0);

    // ---- r-softmax + gate -> wf B-frags in LDS (math identical) ----
#pragma unroll
    for (int mi = 0; mi < 2; ++mi) {
        const int mt = w * 2 + mi;
#pragma unroll
        for (int nt = 0; nt < 4; ++nt) {
            float g = gv[mi][nt];
            float s0 = acc[mi][nt][0] * 0.125f;
            float s1 = acc[mi][nt][1] * 0.125f;
            float s2 = acc[mi][nt][2] * 0.125f;
            float s3 = acc[mi][nt][3] * 0.125f;
            float mx = fmaxf(fmaxf(s0, s1), fmaxf(s2, s3));
            mx = fmaxf(mx, __shfl_xor(mx, 16));
            float e0 = __expf(s0 - mx), e1 = __expf(s1 - mx);
            float e2 = __expf(s2 - mx), e3 = __expf(s3 - mx);
            float loc = (e0 + e1) + (e2 + e3);
            float se = loc + __shfl_xor(loc, 16);
            float ws = g / se;
            int2 pk;
            pk.x = pk2(e0 * ws, e1 * ws);
            pk.y = pk2(e2 * ws, e3 * ws);
            int off = (((mt & 1) * 2 + (l4 >> 1)) * 16 + l15) * 8 + (l4 & 1) * 4;
            *(int2*)&wf[(nt * 8 + (mt >> 1)) * 512 + off] = pk;
        }
    }
    __syncthreads();

    // ---- heads GEMM: wave w -> d-tile = w&3, n-tiles = (w>>2)*2 .. +1 ----
    const int dt = w & 3;
    const int nt0 = (w >> 2) * 2;
    floatx4 h4[2] = {};
#pragma unroll
    for (int kb = 0; kb < 8; ++kb) {
        short8 va = *(const short8*)((const short*)vfrag +
                      ((size_t)(h * 32 + dt * 8 + kb) * 512 + lane * 8));
#pragma unroll
        for (int j = 0; j < 2; ++j) {
            short8 wb = *(const short8*)&wf[((nt0 + j) * 8 + kb) * 512 + lane * 8];
            h4[j] = __builtin_amdgcn_mfma_f32_16x16x32_bf16(va, wb, h4[j], 0, 0, 0);
        }
    }
#pragma unroll
    for (int j = 0; j < 2; ++j) {
        int t = t0 + (nt0 + j) * 16 + l15;
        int2 pk;
        pk.x = pk2(h4[j][0], h4[j][1]);
        pk.y = pk2(h4[j][2], h4[j][3]);
        *(int2*)((short*)hb + (size_t)t * DM + h * 64 + dt * 16 + l4 * 4) = pk;
    }
}

// ---------------------------------------------------------------------------
// Kernel 3 (v8): 8-wave occupancy GEMM. Unchanged from R13/R14 (out of
// top-5, < 47.5 us).
// ---------------------------------------------------------------------------
__global__ __launch_bounds__(512, 4) void gemm_v8(const __hip_bfloat16* __restrict__ Abf,
                                                  const __hip_bfloat16* __restrict__ Bsw,
                                                  const float* __restrict__ bias,
                                                  float* __restrict__ C) {
    __shared__ __align__(16) short As[2][8192];   // 2 x [128 rows][64 k] bf16, swizzled
    const int lane = threadIdx.x & 63;
    const int wave = threadIdx.x >> 6;            // 0..7
    const int wm = wave >> 2, wn = wave & 3;      // 2 x 4 wave grid

    const int wg  = blockIdx.y * 8 + blockIdx.x;  // 0..1023
    const int xcd = wg & 7;
    const int loc = wg >> 3;                      // 0..127
    const int bm0 = (xcd * 16 + (loc >> 3)) * 128;
    const int bn0 = (loc & 7) * 128;

    const int l15 = lane & 15, l4 = lane >> 4;

    const short* Ap = (const short*)Abf;
    const short* Bp = (const short*)Bsw;

    int crow[2], ck8[2];
#pragma unroll
    for (int j = 0; j < 2; ++j) {
        int c = (wave * 2 + j) * 64 + lane;
        int row = c >> 3;
        crow[j] = row;
        ck8[j] = ((c & 7) ^ (row & 7)) * 8;
    }

    int boff[2];
#pragma unroll
    for (int nt = 0; nt < 2; ++nt)
        boff[nt] = (((bn0 >> 4) + wn * 2 + nt) * 32) * 512 + lane * 8;

    const int axor = l15 & 7;
    int arow[4];
#pragma unroll
    for (int mt = 0; mt < 4; ++mt)
        arow[mt] = (wm * 64 + mt * 16 + l15) * 64;
    const int ak0 = (l4 ^ axor) * 8;              // kbi = 0
    const int ak1 = ((4 + l4) ^ axor) * 8;        // kbi = 1

    floatx4 acc[4][2] = {};

    // ---- prologue: stage step 0 into buf 0, load B(0, kbi0) ----
#pragma unroll
    for (int j = 0; j < 2; ++j)
        __builtin_amdgcn_global_load_lds(
            (const __attribute__((address_space(1))) unsigned int*)
                (Ap + (size_t)(bm0 + crow[j]) * KK + ck8[j]),
            (__attribute__((address_space(3))) unsigned int*)&As[0][(wave * 2 + j) * 512],
            16, 0, 0);
    short8 bA[2];
#pragma unroll
    for (int nt = 0; nt < 2; ++nt)
        bA[nt] = *(const short8*)(Bp + boff[nt]);
    __syncthreads();                              // buf0 staged, bA ready

    for (int step = 0; step < 16; ++step) {
        const int cur = step & 1;
        const int nxt = cur ^ 1;

        short8 bB[2];
#pragma unroll
        for (int nt = 0; nt < 2; ++nt)
            bB[nt] = *(const short8*)(Bp + boff[nt] + (size_t)(2 * step + 1) * 512);

        short8 bN[2];
        if (step < 15) {
#pragma unroll
            for (int nt = 0; nt < 2; ++nt)
                bN[nt] = *(const short8*)(Bp + boff[nt] + (size_t)(2 * step + 2) * 512);
#pragma unroll
            for (int j = 0; j < 2; ++j)
                __builtin_amdgcn_global_load_lds(
                    (const __attribute__((address_space(1))) unsigned int*)
                        (Ap + (size_t)(bm0 + crow[j]) * KK + (step + 1) * 64 + ck8[j]),
                    (__attribute__((address_space(3))) unsigned int*)&As[nxt][(wave * 2 + j) * 512],
                    16, 0, 0);
        }

        // ---- kbi = 0 (kb = 2*step) ----
        short8 a0[4];
#pragma unroll
        for (int mt = 0; mt < 4; ++mt)
            a0[mt] = *(const short8*)&As[cur][arow[mt] + ak0];
#pragma unroll
        for (int mt = 0; mt < 4; ++mt)
#pragma unroll
            for (int nt = 0; nt < 2; ++nt)
                acc[mt][nt] = __builtin_amdgcn_mfma_f32_16x16x32_bf16(a0[mt], bA[nt], acc[mt][nt], 0, 0, 0);

        // ---- kbi = 1 (kb = 2*step+1) ----
        short8 a1[4];
#pragma unroll
        for (int mt = 0; mt < 4; ++mt)
            a1[mt] = *(const short8*)&As[cur][arow[mt] + ak1];
#pragma unroll
        for (int mt = 0; mt < 4; ++mt)
#pragma unroll
            for (int nt = 0; nt < 2; ++nt)
                acc[mt][nt] = __builtin_amdgcn_mfma_f32_16x16x32_bf16(a1[mt], bB[nt], acc[mt][nt], 0, 0, 0);

        if (step < 15) {
#pragma unroll
            for (int nt = 0; nt < 2; ++nt)
                bA[nt] = bN[nt];
        }
        __syncthreads();
    }

#pragma unroll
    for (int nt = 0; nt < 2; ++nt) {
        const int col = bn0 + wn * 32 + nt * 16 + l15;
        const float bv = bias[col];
#pragma unroll
        for (int mt = 0; mt < 4; ++mt) {
            const int row0 = bm0 + wm * 64 + mt * 16 + l4 * 4;
#pragma unroll
            for (int i = 0; i < 4; ++i)
                C[(size_t)(row0 + i) * NN + col] = acc[mt][nt][i] + bv;
        }
    }
}

// ---------------------------------------------------------------------------
extern "C" void kernel_launch(void* const* d_in, const int* in_sizes, int n_in,
                              void* d_out, int out_size, void* d_ws, size_t ws_size,
                              hipStream_t stream) {
    const float* x   = (const float*)d_in[0];
    const float* Kst = (const float*)d_in[1];
    const float* Vst = (const float*)d_in[2];
    const float* Wr  = (const float*)d_in[3];
    const float* Wo  = (const float*)d_in[4];
    const float* bo  = (const float*)d_in[5];
    const int*   kp  = (const int*)d_in[6];
    float* out = (float*)d_out;

    __hip_bfloat16* hb    = (__hip_bfloat16*)d_ws;             // 16M bf16 = 32 MiB
    __hip_bfloat16* wsw   = hb + (size_t)MM * KK;              // 1M bf16  = 2 MiB
    __hip_bfloat16* kfrag = wsw + (size_t)KK * NN;             // 256K bf16
    __hip_bfloat16* vfrag = kfrag + 16 * 32 * 512;             // 256K bf16
    float* gates_g = (float*)(vfrag + 16 * 32 * 512);          // 2M f32 = 8 MiB
    // xbf (32 MiB) aliases d_out (64 MiB): consumed by attn_mm8, then gemm
    // overwrites every element of C.
    __hip_bfloat16* xbf = (__hip_bfloat16*)d_out;

    pre_fused<<<dim3(4864), 256, 0, stream>>>(x, Wr, kp, Wo, Kst, Vst,
                                              gates_g, wsw, kfrag, vfrag, xbf);
    attn_mm8<<<dim3(NTOK / 64, HH), 512, 0, stream>>>(xbf, kfrag, vfrag, gates_g, hb);
    gemm_v8<<<dim3(NN / 128, MM / 128), 512, 0, stream>>>(hb, wsw, bo, out);
}

// Round 16
// 214.954 us; speedup vs baseline: 1.0291x; 1.0291x over previous
//
#include <hip/hip_runtime.h>
#include <hip/hip_bf16.h>

// Problem constants
#define BB 4
#define SS 4096
#define DM 1024
#define HH 16
#define PP 32
#define RR 8
#define DD 64
#define NTOK (BB*SS)          // 16384 tokens
#define MM NTOK               // GEMM M
#define NN DM                 // GEMM N
#define KK DM                 // GEMM K

typedef __attribute__((ext_vector_type(8))) short short8;
typedef __attribute__((ext_vector_type(4))) float floatx4;
typedef __attribute__((ext_vector_type(2))) float floatx2;

static __device__ inline short f2bf(float f) {
    union { __hip_bfloat16 b; short s; } u; u.b = __float2bfloat16(f); return u.s;
}
static __device__ inline short8 pack8(float4 lo, float4 hi) {
    short8 r;
    r[0] = f2bf(lo.x); r[1] = f2bf(lo.y); r[2] = f2bf(lo.z); r[3] = f2bf(lo.w);
    r[4] = f2bf(hi.x); r[5] = f2bf(hi.y); r[6] = f2bf(hi.z); r[7] = f2bf(hi.w);
    return r;
}

// Fast RNE bf16 pack: identical bits to __float2bfloat16 for finite inputs.
static __device__ inline unsigned bfr(float f) {
    unsigned u = __float_as_uint(f);
    return u + 0x7fffu + ((u >> 16) & 1u);
}
static __device__ inline int pk2(float a, float b) {  // low16=bf(a), high16=bf(b)
    return __builtin_amdgcn_perm(bfr(b), bfr(a), 0x07060302);
}
static __device__ inline short8 pk8(float4 lo, float4 hi) {
    union { short8 s; int i[4]; } r;
    r.i[0] = pk2(lo.x, lo.y); r.i[1] = pk2(lo.z, lo.w);
    r.i[2] = pk2(hi.x, hi.y); r.i[3] = pk2(hi.z, hi.w);
    return r.s;
}

// Exact top-4 ladder insert: selection network (fmax/fmin only), order-
// independent — produces exact order statistics, no rounding.
#define LADDER_INSERT(v_, aa_, b2_, c3_, d4_)                  \
    {                                                          \
        float v = (v_);                                        \
        float na = fmaxf(aa_, v); v = fminf(aa_, v); aa_ = na; \
        float nb = fmaxf(b2_, v); v = fminf(b2_, v); b2_ = nb; \
        float nc = fmaxf(c3_, v); v = fminf(c3_, v); c3_ = nc; \
        d4_ = fmaxf(d4_, v);                                   \
    }

// ---------------------------------------------------------------------------
// Kernel 1 (pre_fused v3): router+packer ∥ weight converts. Unchanged from
// R15 (declared local optimum: 3 rounds of attacks moved it 48.6 -> 47.0).
// ---------------------------------------------------------------------------
__global__ __launch_bounds__(256) void pre_fused(const float* __restrict__ x,
                                                 const float* __restrict__ Wr,
                                                 const int* __restrict__ kp,
                                                 const float* __restrict__ Wo,
                                                 const float* __restrict__ Kst,
                                                 const float* __restrict__ Vst,
                                                 float* __restrict__ gates_g,
                                                 __hip_bfloat16* __restrict__ wsw,
                                                 __hip_bfloat16* __restrict__ kfrag,
                                                 __hip_bfloat16* __restrict__ vfrag,
                                                 __hip_bfloat16* __restrict__ xbf) {
    const int bx = blockIdx.x;

    if (bx >= 4096) {
        if (bx < 4608) {                        // ---- convert_w ----
            int tid = (bx - 4096) * 256 + threadIdx.x;     // 0 .. 131071
            int l = tid & 63;
            int kblk = (tid >> 6) & 31;
            int ntile = tid >> 11;
            int col = ntile * 16 + (l & 15);
            int krow = kblk * 32 + (l >> 4) * 8;
#pragma unroll
            for (int j = 0; j < 8; ++j)
                wsw[(size_t)tid * 8 + j] = __float2bfloat16(Wo[(size_t)(krow + j) * NN + col]);
        } else {                                // ---- convert_kv ----
            int tid = (bx - 4608) * 256 + threadIdx.x;     // 0..65535
            int arr = tid >> 15;
            int idx = tid & 32767;
            int h = idx >> 11, blk = (idx >> 6) & 31, fl = idx & 63;
            int fm = fl & 15, fk = fl >> 4;
            short8 val;
            short* dst;
            if (arr == 0) {
                int mt = blk >> 1, kb = blk & 1;
                int pr = mt * 16 + fm, d0 = kb * 32 + fk * 8;
                const float* src = Kst + ((size_t)h * 256 + pr) * 64 + d0;
                float4 lo = *(const float4*)src, hi = *(const float4*)(src + 4);
                val = pack8(lo, hi);
                dst = (short*)kfrag + (size_t)idx * 8;
            } else {
                int mt = blk >> 3, kb = blk & 7;
                int d = mt * 16 + fm, pr0 = kb * 32 + fk * 8;
                const float* src = Vst + ((size_t)h * 256 + pr0) * 64 + d;
#pragma unroll
                for (int j = 0; j < 8; ++j) val[j] = f2bf(src[j * 64]);
                dst = (short*)vfrag + (size_t)idx * 8;
            }
            *(short8*)dst = val;
        }
        return;
    }

    // ------------------------- router branch -------------------------
    __shared__ __align__(16) char smem[26624];
    float (*xs)[68] = (float (*)[68])smem;               // [0,17408)
    float (*Lg)[36] = (float (*)[36])(smem + 17408);     // [17408,26624)

    const int lane = threadIdx.x & 63;
    const int w = threadIdx.x >> 6;
    const int l15 = lane & 15, l4 = lane >> 4;
    const int tile = bx & 255;
    const int h = bx >> 8;
    const int t0 = tile * 64;

    // ---- stage x tile [64 t x 64 d] into LDS ----
    {
        int row = threadIdx.x >> 2, q = threadIdx.x & 3;
        const float4* src = (const float4*)(x + (size_t)(t0 + row) * DM + h * 64 + q * 16);
        float4 v0 = src[0], v1 = src[1], v2 = src[2], v3 = src[3];
        float4* dst = (float4*)&xs[row][q * 16];
        dst[0] = v0; dst[1] = v1; dst[2] = v2; dst[3] = v3;
    }

    // ---- fused xbf packer (reads L1/L2-hot x; exact R13 packer bits) ----
    {
        const float* srcb = x + (size_t)(t0 + w * 16 + l15) * DM + h * 64 + l4 * 8;
        short* dstb = (short*)xbf + ((size_t)((h * 256 + tile) * 8 + w * 2) * 512) + lane * 8;
#pragma unroll
        for (int kb = 0; kb < 2; ++kb) {
            float4 lo = *(const float4*)(srcb + kb * 32);
            float4 hi = *(const float4*)(srcb + kb * 32 + 4);
            *(short8*)(dstb + kb * 512) = pk8(lo, hi);
        }
    }

    // ---- preload router weights (exact R1 pattern) ----
    const int p = lane & 31, dh = lane >> 5;
    float wreg[32];
    {
        const float* wrp = Wr + (size_t)h * (DD * PP) + dh * 32 * PP + p;
#pragma unroll
        for (int dd = 0; dd < 32; ++dd) wreg[dd] = wrp[dd * PP];
    }
    const int kkv = kp[0];

    __syncthreads();

    // ---- logits: packed float2 (tokens A,B | C,D); per-component fma
    //      chain IDENTICAL to the scalar fmac chain -> bit-identical ----
    for (int it = 0; it < 16; it += 4) {
        const int ta = w * 16 + it;
        floatx2 lab = {0.f, 0.f}, lcd = {0.f, 0.f};
#pragma unroll
        for (int j = 0; j < 8; ++j) {
            float4 qa = *(const float4*)&xs[ta + 0][dh * 32 + 4 * j];
            float4 qb = *(const float4*)&xs[ta + 1][dh * 32 + 4 * j];
            float4 qc = *(const float4*)&xs[ta + 2][dh * 32 + 4 * j];
            float4 qd = *(const float4*)&xs[ta + 3][dh * 32 + 4 * j];
            floatx2 w0 = {wreg[4 * j], wreg[4 * j]};
            floatx2 w1 = {wreg[4 * j + 1], wreg[4 * j + 1]};
            floatx2 w2 = {wreg[4 * j + 2], wreg[4 * j + 2]};
            floatx2 w3 = {wreg[4 * j + 3], wreg[4 * j + 3]};
            floatx2 vx, vy, vz, vw, ux, uy, uz, uw;
            vx[0] = qa.x; vx[1] = qb.x;  ux[0] = qc.x; ux[1] = qd.x;
            vy[0] = qa.y; vy[1] = qb.y;  uy[0] = qc.y; uy[1] = qd.y;
            vz[0] = qa.z; vz[1] = qb.z;  uz[0] = qc.z; uz[1] = qd.z;
            vw[0] = qa.w; vw[1] = qb.w;  uw[0] = qc.w; uw[1] = qd.w;
            lab = __builtin_elementwise_fma(vx, w0, lab);
            lcd = __builtin_elementwise_fma(ux, w0, lcd);
            lab = __builtin_elementwise_fma(vy, w1, lab);
            lcd = __builtin_elementwise_fma(uy, w1, lcd);
            lab = __builtin_elementwise_fma(vz, w2, lab);
            lcd = __builtin_elementwise_fma(uz, w2, lcd);
            lab = __builtin_elementwise_fma(vw, w3, lab);
            lcd = __builtin_elementwise_fma(uw, w3, lcd);
        }
        float la = lab[0], lb = lab[1], lc = lcd[0], ld = lcd[1];
        la += __shfl_xor(la, 32);
        lb += __shfl_xor(lb, 32);
        lc += __shfl_xor(lc, 32);
        ld += __shfl_xor(ld, 32);
        if (lane < 32) {
            Lg[ta + 0][lane] = la;
            Lg[ta + 1][lane] = lb;
            Lg[ta + 2][lane] = lc;
            Lg[ta + 3][lane] = ld;
        }
    }
    __syncthreads();

    // ---- top-k: 64-lane parallel EXACT selection (R15, verified) ----
    float thresh, a1;
    {
        const int t = w * 16 + l15;
        const float4* lrow = (const float4*)&Lg[t][l4 * 8];
        float4 qa = lrow[0], qb = lrow[1];
        float aa = -INFINITY, b2 = -INFINITY, c3 = -INFINITY, d4 = -INFINITY;
        LADDER_INSERT(qa.x, aa, b2, c3, d4);
        LADDER_INSERT(qa.y, aa, b2, c3, d4);
        LADDER_INSERT(qa.z, aa, b2, c3, d4);
        LADDER_INSERT(qa.w, aa, b2, c3, d4);
        LADDER_INSERT(qb.x, aa, b2, c3, d4);
        LADDER_INSERT(qb.y, aa, b2, c3, d4);
        LADDER_INSERT(qb.z, aa, b2, c3, d4);
        LADDER_INSERT(qb.w, aa, b2, c3, d4);
#pragma unroll
        for (int m = 16; m <= 32; m <<= 1) {
            float pa = __shfl_xor(aa, m);
            float pb = __shfl_xor(b2, m);
            float pc = __shfl_xor(c3, m);
            float pd = __shfl_xor(d4, m);
            LADDER_INSERT(pa, aa, b2, c3, d4);
            LADDER_INSERT(pb, aa, b2, c3, d4);
            LADDER_INSERT(pc, aa, b2, c3, d4);
            LADDER_INSERT(pd, aa, b2, c3, d4);
        }
        thresh = (kkv >= 4) ? d4 : (kkv == 3 ? c3 : (kkv == 2 ? b2 : aa));
        a1 = aa;
    }

    // ---- gates: all 64 lanes, 8 p-values each; values identical ----
    {
        const int t = w * 16 + l15;
        const int p8 = l4 * 8;
        const float4* lrow = (const float4*)&Lg[t][p8];
        float4 qa = lrow[0], qb = lrow[1];
        float e0 = (qa.x >= thresh) ? __expf(qa.x - a1) : 0.f;
        float e1 = (qa.y >= thresh) ? __expf(qa.y - a1) : 0.f;
        float e2 = (qa.z >= thresh) ? __expf(qa.z - a1) : 0.f;
        float e3 = (qa.w >= thresh) ? __expf(qa.w - a1) : 0.f;
        float e4 = (qb.x >= thresh) ? __expf(qb.x - a1) : 0.f;
        float e5 = (qb.y >= thresh) ? __expf(qb.y - a1) : 0.f;
        float e6 = (qb.z >= thresh) ? __expf(qb.z - a1) : 0.f;
        float e7 = (qb.w >= thresh) ? __expf(qb.w - a1) : 0.f;
        float part = ((e0 + e1) + (e2 + e3)) + ((e4 + e5) + (e6 + e7));
        part += __shfl_xor(part, 16);
        part += __shfl_xor(part, 32);
        float inv = 1.f / part;
        float* gb = gates_g + ((size_t)(h * 256 + tile) * 32) * 64 + t;
        gb[(p8 + 0) * 64] = e0 * inv;
        gb[(p8 + 1) * 64] = e1 * inv;
        gb[(p8 + 2) * 64] = e2 * inv;
        gb[(p8 + 3) * 64] = e3 * inv;
        gb[(p8 + 4) * 64] = e4 * inv;
        gb[(p8 + 5) * 64] = e5 * inv;
        gb[(p8 + 6) * 64] = e6 * inv;
        gb[(p8 + 7) * 64] = e7 * inv;
    }
}

// ---------------------------------------------------------------------------
// Kernel 2 (attn_mm8 v2): vfrag loads HOISTED above the scores MFMA.
// R15 structure ate the full L2 latency of the 8 vfrag loads serially in
// the heads phase (issued after the barrier — the same pattern that cost
// gemm_v5 10 us). They depend on nothing: issue them with the other global
// loads so they complete under scores+wf+barrier (~600 cyc of cover).
// +32 VGPR (va[8]); est ~113 <= 128 cap at (512,4). Math bit-identical.
// ---------------------------------------------------------------------------
__global__ __launch_bounds__(512, 4) void attn_mm8(const __hip_bfloat16* __restrict__ xbf,
                                                   const __hip_bfloat16* __restrict__ kfrag,
                                                   const __hip_bfloat16* __restrict__ vfrag,
                                                   const float* __restrict__ gates_g,
                                                   __hip_bfloat16* __restrict__ hb) {
    __shared__ __align__(16) short wf[16384];      // 32768 B

    const int lane = threadIdx.x & 63;
    const int w = threadIdx.x >> 6;                // 0..7
    const int l15 = lane & 15, l4 = lane >> 4;
    const int t0 = blockIdx.x * 64;
    const int h = blockIdx.y;
    const int dt = w & 3;
    const int nt0 = (w >> 2) * 2;

    // ---- preload gates (global, written by pre_fused) ----
    const float* gb = gates_g + ((size_t)(h * 256 + blockIdx.x) * 32) * 64;
    float gv[2][4];
#pragma unroll
    for (int mi = 0; mi < 2; ++mi) {
        const int pidx = (w * 2 + mi) * 2 + (l4 >> 1);
#pragma unroll
        for (int nt = 0; nt < 4; ++nt)
            gv[mi][nt] = gb[pidx * 64 + nt * 16 + l15];
    }

    // ---- scores GEMM operand loads: pre-packed bf16 fragments ----
    const short* xbase = (const short*)xbf + ((size_t)(h * 256 + blockIdx.x) * 8) * 512 + lane * 8;
    short8 xb[4][2];
#pragma unroll
    for (int nt = 0; nt < 4; ++nt)
#pragma unroll
        for (int kb = 0; kb < 2; ++kb)
            xb[nt][kb] = *(const short8*)(xbase + (nt * 2 + kb) * 512);
    short8 ka[2][2];                               // mt = w*2 + mi
#pragma unroll
    for (int mi = 0; mi < 2; ++mi)
#pragma unroll
        for (int kb = 0; kb < 2; ++kb)
            ka[mi][kb] = *(const short8*)((const short*)kfrag +
                          ((size_t)(h * 32 + (w * 2 + mi) * 2 + kb) * 512 + lane * 8));

    // ---- EARLY: heads A-operand (vfrag) — no dependencies; latency hides
    //      under scores MFMA + wf phase + barrier ----
    short8 va[8];
#pragma unroll
    for (int kb = 0; kb < 8; ++kb)
        va[kb] = *(const short8*)((const short*)vfrag +
                      ((size_t)(h * 32 + dt * 8 + kb) * 512 + lane * 8));

    // ---- scores GEMM: S^T[pr][t]; per-element kb chains identical ----
    floatx4 acc[2][4] = {};
#pragma unroll
    for (int kb = 0; kb < 2; ++kb)
#pragma unroll
        for (int mi = 0; mi < 2; ++mi)
#pragma unroll
            for (int nt = 0; nt < 4; ++nt)
                acc[mi][nt] = __builtin_amdgcn_mfma_f32_16x16x32_bf16(ka[mi][kb], xb[nt][kb], acc[mi][nt], 0, 0, 0);

    // ---- r-softmax + gate -> wf B-frags in LDS (math identical) ----
#pragma unroll
    for (int mi = 0; mi < 2; ++mi) {
        const int mt = w * 2 + mi;
#pragma unroll
        for (int nt = 0; nt < 4; ++nt) {
            float g = gv[mi][nt];
            float s0 = acc[mi][nt][0] * 0.125f;
            float s1 = acc[mi][nt][1] * 0.125f;
            float s2 = acc[mi][nt][2] * 0.125f;
            float s3 = acc[mi][nt][3] * 0.125f;
            float mx = fmaxf(fmaxf(s0, s1), fmaxf(s2, s3));
            mx = fmaxf(mx, __shfl_xor(mx, 16));
            float e0 = __expf(s0 - mx), e1 = __expf(s1 - mx);
            float e2 = __expf(s2 - mx), e3 = __expf(s3 - mx);
            float loc = (e0 + e1) + (e2 + e3);
            float se = loc + __shfl_xor(loc, 16);
            float ws = g / se;
            int2 pk;
            pk.x = pk2(e0 * ws, e1 * ws);
            pk.y = pk2(e2 * ws, e3 * ws);
            int off = (((mt & 1) * 2 + (l4 >> 1)) * 16 + l15) * 8 + (l4 & 1) * 4;
            *(int2*)&wf[(nt * 8 + (mt >> 1)) * 512 + off] = pk;
        }
    }
    __syncthreads();

    // ---- heads GEMM: wave w -> d-tile = w&3, n-tiles = nt0..nt0+1;
    //      A-operand already in registers (va) ----
    floatx4 h4[2] = {};
#pragma unroll
    for (int kb = 0; kb < 8; ++kb) {
#pragma unroll
        for (int j = 0; j < 2; ++j) {
            short8 wb = *(const short8*)&wf[((nt0 + j) * 8 + kb) * 512 + lane * 8];
            h4[j] = __builtin_amdgcn_mfma_f32_16x16x32_bf16(va[kb], wb, h4[j], 0, 0, 0);
        }
    }
#pragma unroll
    for (int j = 0; j < 2; ++j) {
        int t = t0 + (nt0 + j) * 16 + l15;
        int2 pk;
        pk.x = pk2(h4[j][0], h4[j][1]);
        pk.y = pk2(h4[j][2], h4[j][3]);
        *(int2*)((short*)hb + (size_t)t * DM + h * 64 + dt * 16 + l4 * 4) = pk;
    }
}

// ---------------------------------------------------------------------------
// Kernel 3 (v8): 8-wave occupancy GEMM. Unchanged from R13-R15 (out of
// top-5, < 47.5 us).
// ---------------------------------------------------------------------------
__global__ __launch_bounds__(512, 4) void gemm_v8(const __hip_bfloat16* __restrict__ Abf,
                                                  const __hip_bfloat16* __restrict__ Bsw,
                                                  const float* __restrict__ bias,
                                                  float* __restrict__ C) {
    __shared__ __align__(16) short As[2][8192];   // 2 x [128 rows][64 k] bf16, swizzled
    const int lane = threadIdx.x & 63;
    const int wave = threadIdx.x >> 6;            // 0..7
    const int wm = wave >> 2, wn = wave & 3;      // 2 x 4 wave grid

    const int wg  = blockIdx.y * 8 + blockIdx.x;  // 0..1023
    const int xcd = wg & 7;
    const int loc = wg >> 3;                      // 0..127
    const int bm0 = (xcd * 16 + (loc >> 3)) * 128;
    const int bn0 = (loc & 7) * 128;

    const int l15 = lane & 15, l4 = lane >> 4;

    const short* Ap = (const short*)Abf;
    const short* Bp = (const short*)Bsw;

    int crow[2], ck8[2];
#pragma unroll
    for (int j = 0; j < 2; ++j) {
        int c = (wave * 2 + j) * 64 + lane;
        int row = c >> 3;
        crow[j] = row;
        ck8[j] = ((c & 7) ^ (row & 7)) * 8;
    }

    int boff[2];
#pragma unroll
    for (int nt = 0; nt < 2; ++nt)
        boff[nt] = (((bn0 >> 4) + wn * 2 + nt) * 32) * 512 + lane * 8;

    const int axor = l15 & 7;
    int arow[4];
#pragma unroll
    for (int mt = 0; mt < 4; ++mt)
        arow[mt] = (wm * 64 + mt * 16 + l15) * 64;
    const int ak0 = (l4 ^ axor) * 8;              // kbi = 0
    const int ak1 = ((4 + l4) ^ axor) * 8;        // kbi = 1

    floatx4 acc[4][2] = {};

    // ---- prologue: stage step 0 into buf 0, load B(0, kbi0) ----
#pragma unroll
    for (int j = 0; j < 2; ++j)
        __builtin_amdgcn_global_load_lds(
            (const __attribute__((address_space(1))) unsigned int*)
                (Ap + (size_t)(bm0 + crow[j]) * KK + ck8[j]),
            (__attribute__((address_space(3))) unsigned int*)&As[0][(wave * 2 + j) * 512],
            16, 0, 0);
    short8 bA[2];
#pragma unroll
    for (int nt = 0; nt < 2; ++nt)
        bA[nt] = *(const short8*)(Bp + boff[nt]);
    __syncthreads();                              // buf0 staged, bA ready

    for (int step = 0; step < 16; ++step) {
        const int cur = step & 1;
        const int nxt = cur ^ 1;

        short8 bB[2];
#pragma unroll
        for (int nt = 0; nt < 2; ++nt)
            bB[nt] = *(const short8*)(Bp + boff[nt] + (size_t)(2 * step + 1) * 512);

        short8 bN[2];
        if (step < 15) {
#pragma unroll
            for (int nt = 0; nt < 2; ++nt)
                bN[nt] = *(const short8*)(Bp + boff[nt] + (size_t)(2 * step + 2) * 512);
#pragma unroll
            for (int j = 0; j < 2; ++j)
                __builtin_amdgcn_global_load_lds(
                    (const __attribute__((address_space(1))) unsigned int*)
                        (Ap + (size_t)(bm0 + crow[j]) * KK + (step + 1) * 64 + ck8[j]),
                    (__attribute__((address_space(3))) unsigned int*)&As[nxt][(wave * 2 + j) * 512],
                    16, 0, 0);
        }

        // ---- kbi = 0 (kb = 2*step) ----
        short8 a0[4];
#pragma unroll
        for (int mt = 0; mt < 4; ++mt)
            a0[mt] = *(const short8*)&As[cur][arow[mt] + ak0];
#pragma unroll
        for (int mt = 0; mt < 4; ++mt)
#pragma unroll
            for (int nt = 0; nt < 2; ++nt)
                acc[mt][nt] = __builtin_amdgcn_mfma_f32_16x16x32_bf16(a0[mt], bA[nt], acc[mt][nt], 0, 0, 0);

        // ---- kbi = 1 (kb = 2*step+1) ----
        short8 a1[4];
#pragma unroll
        for (int mt = 0; mt < 4; ++mt)
            a1[mt] = *(const short8*)&As[cur][arow[mt] + ak1];
#pragma unroll
        for (int mt = 0; mt < 4; ++mt)
#pragma unroll
            for (int nt = 0; nt < 2; ++nt)
                acc[mt][nt] = __builtin_amdgcn_mfma_f32_16x16x32_bf16(a1[mt], bB[nt], acc[mt][nt], 0, 0, 0);

        if (step < 15) {
#pragma unroll
            for (int nt = 0; nt < 2; ++nt)
                bA[nt] = bN[nt];
        }
        __syncthreads();
    }

#pragma unroll
    for (int nt = 0; nt < 2; ++nt) {
        const int col = bn0 + wn * 32 + nt * 16 + l15;
        const float bv = bias[col];
#pragma unroll
        for (int mt = 0; mt < 4; ++mt) {
            const int row0 = bm0 + wm * 64 + mt * 16 + l4 * 4;
#pragma unroll
            for (int i = 0; i < 4; ++i)
                C[(size_t)(row0 + i) * NN + col] = acc[mt][nt][i] + bv;
        }
    }
}

// ---------------------------------------------------------------------------
extern "C" void kernel_launch(void* const* d_in, const int* in_sizes, int n_in,
                              void* d_out, int out_size, void* d_ws, size_t ws_size,
                              hipStream_t stream) {
    const float* x   = (const float*)d_in[0];
    const float* Kst = (const float*)d_in[1];
    const float* Vst = (const float*)d_in[2];
    const float* Wr  = (const float*)d_in[3];
    const float* Wo  = (const float*)d_in[4];
    const float* bo  = (const float*)d_in[5];
    const int*   kp  = (const int*)d_in[6];
    float* out = (float*)d_out;

    __hip_bfloat16* hb    = (__hip_bfloat16*)d_ws;             // 16M bf16 = 32 MiB
    __hip_bfloat16* wsw   = hb + (size_t)MM * KK;              // 1M bf16  = 2 MiB
    __hip_bfloat16* kfrag = wsw + (size_t)KK * NN;             // 256K bf16
    __hip_bfloat16* vfrag = kfrag + 16 * 32 * 512;             // 256K bf16
    float* gates_g = (float*)(vfrag + 16 * 32 * 512);          // 2M f32 = 8 MiB
    // xbf (32 MiB) aliases d_out (64 MiB): consumed by attn_mm8, then gemm
    // overwrites every element of C.
    __hip_bfloat16* xbf = (__hip_bfloat16*)d_out;

    pre_fused<<<dim3(4864), 256, 0, stream>>>(x, Wr, kp, Wo, Kst, Vst,
                                              gates_g, wsw, kfrag, vfrag, xbf);
    attn_mm8<<<dim3(NTOK / 64, HH), 512, 0, stream>>>(xbf, kfrag, vfrag, gates_g, hb);
    gemm_v8<<<dim3(NN / 128, MM / 128), 512, 0, stream>>>(hb, wsw, bo, out);
}